// Round 13
// baseline (527.292 us; speedup 1.0000x reference)
//
#include <hip/hip_runtime.h>
#include <hip/hip_bf16.h>

#define Hh 16
#define Nn 8192
#define Dd 64
#define NB 128

typedef float  f32x4   __attribute__((ext_vector_type(4)));
typedef float  f32x16  __attribute__((ext_vector_type(16)));
typedef float  float4_ __attribute__((ext_vector_type(4)));
typedef short  bf16x8  __attribute__((ext_vector_type(8)));
typedef unsigned short ushort8  __attribute__((ext_vector_type(8)));
typedef unsigned short ushort4_ __attribute__((ext_vector_type(4)));

// log2(e) / sqrt(64) — folded into Q so QK^T lands in log2 domain
#define QSCALE 0.1803368801111244f

__device__ __forceinline__ unsigned short f2bf(float f) {
    union { float f; unsigned u; } x; x.f = f;
    unsigned r = x.u + 0x7fffu + ((x.u >> 16) & 1u);  // RNE
    return (unsigned short)(r >> 16);
}

// compiler-recognized pack: emits a single v_cvt_pk_bf16_f32 (RNE)
__device__ __forceinline__ unsigned packbf2(float lo, float hi) {
    __hip_bfloat162 h2 = __float22bfloat162_rn(make_float2(lo, hi));
    unsigned u; __builtin_memcpy(&u, &h2, 4);
    return u;
}

// ---- pre-pass 1: k -> bf16
__global__ void cvt_k(const float* __restrict__ k, unsigned short* __restrict__ ko) {
    int i = blockIdx.x * 256 + threadIdx.x;
    float4_ b = ((const float4_*)k)[i];
    ushort4_ ob;
#pragma unroll
    for (int j = 0; j < 4; ++j) ob[j] = f2bf(b[j]);
    ((ushort4_*)ko)[i] = ob;
}

// ---- pre-pass 2: v -> vt[h][d][n] bf16 (per-head transpose)
__global__ void cvt_vt(const float* __restrict__ v, unsigned short* __restrict__ vt) {
    int jb = blockIdx.x, h = blockIdx.y, t = threadIdx.x;
    __shared__ float T[64][65];
    const float4_* src = (const float4_*)(v + ((long)h * Nn + jb * 64) * Dd);
#pragma unroll
    for (int it = 0; it < 4; ++it) {
        int r = (t >> 4) + it * 16;
        int c0 = (t & 15) * 4;
        float4_ x = src[r * 16 + (t & 15)];
#pragma unroll
        for (int i2 = 0; i2 < 4; ++i2) T[c0 + i2][r] = x[i2];
    }
    __syncthreads();
    int d = t >> 2, seg = (t & 3) * 16;
    ushort8 o0, o1;
#pragma unroll
    for (int i2 = 0; i2 < 8; ++i2) o0[i2] = f2bf(T[d][seg + i2]);
#pragma unroll
    for (int i2 = 0; i2 < 8; ++i2) o1[i2] = f2bf(T[d][seg + 8 + i2]);
    unsigned short* dst = vt + ((long)h * Dd + d) * Nn + jb * 64 + seg;
    *(ushort8*)dst = o0;
    *(ushort8*)(dst + 8) = o1;
}

// =====================================================================
// Main: ONE independent wave per (head, 32-query strip). 4096 blocks of
// 64 threads. ZERO barriers, ZERO LDS. K/V staged into registers (exact
// fragment images of the LDS version — round-10-verified numerics,
// absmax 1.46e-3). Round-10's 1069us failure was launch_bounds(64,4)
// forcing 64 VGPR -> ~190-VGPR state spilled to scratch (2.9GB HBM
// writes). Fix: launch_bounds(64,2) = 256-VGPR cap, no spill,
// 2 waves/SIMD. + cvt_pk packing (r11-proven) + s_setprio around MFMA
// clusters (T5, m191: proven on independent-1-wave-block attention).
// Prefetch: K for j+1 issued after QK consumes kst; V after PV.
// =====================================================================
__global__ __launch_bounds__(64, 2) void attn_w(
        const unsigned short* __restrict__ k16,
        const unsigned short* __restrict__ vt16,
        const float* __restrict__ qf,
        const int* __restrict__ mask,
        float* __restrict__ out) {
    int bid = blockIdx.x;
    // bid = i*8 + xcd;  i = hhi*256 + qb*2 + qhalf  (hhi slowest -> one
    // head resident per XCD L2 at a time; sibling q-halves adjacent).
    int xcd = bid & 7;
    int i5 = bid >> 3;
    int hhi = i5 >> 8;
    int qb = (i5 >> 1) & 127;
    int qhalf = i5 & 1;
    int h = xcd | (hhi << 3);
    int l = threadIdx.x;
    int q5 = l & 31, hi = l >> 5;

    const int* mrow = mask + qb * NB;
    unsigned long long b0 = __ballot(mrow[l] != 0);
    unsigned long long b1 = __ballot(mrow[64 + l] != 0);
    int count = __popcll(b0) + __popcll(b1);

    size_t qrow = (size_t)h * Nn + qb * 64 + qhalf * 32 + q5;

    if (count == 0) {
        float4_ z = {0.f, 0.f, 0.f, 0.f};
        float4_* ob = (float4_*)(out + ((size_t)h * Nn + qb * 64 + qhalf * 32) * Dd);
#pragma unroll
        for (int c = 0; c < 8; ++c) ob[(l >> 1) * 16 + (l & 1) * 8 + c] = z;
        return;
    }

    // ---- Q fragments (B-operand: col=q5, k=hi*8+i within d-slice), scale folded
    bf16x8 qfrag[4];
#pragma unroll
    for (int ds_ = 0; ds_ < 4; ++ds_) {
        const float4_* qs = (const float4_*)(qf + qrow * Dd + ds_ * 16 + hi * 8);
        float4_ x = qs[0], y = qs[1];
        union { unsigned u[4]; bf16x8 v; } u;
        u.u[0] = packbf2(x[0] * QSCALE, x[1] * QSCALE);
        u.u[1] = packbf2(x[2] * QSCALE, x[3] * QSCALE);
        u.u[2] = packbf2(y[0] * QSCALE, y[1] * QSCALE);
        u.u[3] = packbf2(y[2] * QSCALE, y[3] * QSCALE);
        qfrag[ds_] = u.v;
    }

    // ---- per-lane fragment source offsets (elements), j-independent
    const unsigned short* kbase = k16 + (size_t)h * (Nn * Dd);
    const unsigned short* vbase = vt16 + (size_t)h * (Nn * Dd);
    int koff[8], voff[8];
#pragma unroll
    for (int f = 0; f < 8; ++f) {
        koff[f] = (q5 + 32 * (f >> 2)) * Dd + (f & 3) * 16 + hi * 8;
        voff[f] = (q5 + 32 * (f >> 2)) * Nn + (f & 3) * 16 + hi * 8;
    }

    unsigned long long r0 = b0, r1 = b1;
    auto next_j = [&]() {
        int jj;
        if (r0) { jj = __ffsll(r0) - 1; r0 &= r0 - 1; }
        else    { jj = 63 + __ffsll(r1); r1 &= r1 - 1; }
        return jj;
    };

    bf16x8 kst[8], vst[8];
    int jn = next_j();
    {
        const unsigned short* kj = kbase + (size_t)jn * (64 * Dd);
        const unsigned short* vj = vbase + (size_t)jn * 64;
#pragma unroll
        for (int f = 0; f < 8; ++f) kst[f] = *(const bf16x8*)(kj + koff[f]);
#pragma unroll
        for (int f = 0; f < 8; ++f) vst[f] = *(const bf16x8*)(vj + voff[f]);
    }

    f32x16 o0 = {}, o1 = {};
    float l_run = 0.f;

    union U { unsigned u[4]; bf16x8 v; };
    U pbs[4];

    auto swap32 = [&](unsigned& a, unsigned& b) {
        unsigned send = hi ? a : b;
        unsigned recv = (unsigned)__shfl_xor((int)send, 32);
        a = hi ? recv : a;
        b = hi ? b : recv;
    };

    for (int it = 0; it < count; ++it) {
        bool have_next = (it + 1 < count);

        // ---- half A: keys 0..31 of this block
        f32x16 s = {};
        __builtin_amdgcn_s_setprio(1);
#pragma unroll
        for (int ds_ = 0; ds_ < 4; ++ds_)
            s = __builtin_amdgcn_mfma_f32_32x32x16_bf16(kst[ds_], qfrag[ds_], s, 0, 0, 0);
        __builtin_amdgcn_s_setprio(0);
#pragma unroll
        for (int e = 0; e < 16; ++e) s[e] = __builtin_amdgcn_exp2f(s[e]);
        float lpA;
        {
            float t8[8];
#pragma unroll
            for (int e = 0; e < 8; ++e) t8[e] = s[e] + s[e + 8];
#pragma unroll
            for (int e = 0; e < 4; ++e) t8[e] += t8[e + 4];
            lpA = (t8[0] + t8[1]) + (t8[2] + t8[3]);
        }
        {
            unsigned w[8];
#pragma unroll
            for (int jj = 0; jj < 8; ++jj) w[jj] = packbf2(s[2 * jj], s[2 * jj + 1]);
            swap32(w[0], w[2]); swap32(w[1], w[3]);
            swap32(w[4], w[6]); swap32(w[5], w[7]);
            pbs[0].u[0] = w[0]; pbs[0].u[1] = w[1]; pbs[0].u[2] = w[2]; pbs[0].u[3] = w[3];
            pbs[1].u[0] = w[4]; pbs[1].u[1] = w[5]; pbs[1].u[2] = w[6]; pbs[1].u[3] = w[7];
        }

        // ---- half B: keys 32..63
        f32x16 s2 = {};
        __builtin_amdgcn_s_setprio(1);
#pragma unroll
        for (int ds_ = 0; ds_ < 4; ++ds_)
            s2 = __builtin_amdgcn_mfma_f32_32x32x16_bf16(kst[4 + ds_], qfrag[ds_], s2, 0, 0, 0);
        __builtin_amdgcn_s_setprio(0);

        // kst fully consumed -> prefetch next block's K (covers softmax B + PV)
        if (have_next) {
            jn = next_j();
            const unsigned short* kj = kbase + (size_t)jn * (64 * Dd);
#pragma unroll
            for (int f = 0; f < 8; ++f) kst[f] = *(const bf16x8*)(kj + koff[f]);
        }

#pragma unroll
        for (int e = 0; e < 16; ++e) s2[e] = __builtin_amdgcn_exp2f(s2[e]);
        float lpB;
        {
            float t8[8];
#pragma unroll
            for (int e = 0; e < 8; ++e) t8[e] = s2[e] + s2[e + 8];
#pragma unroll
            for (int e = 0; e < 4; ++e) t8[e] += t8[e + 4];
            lpB = (t8[0] + t8[1]) + (t8[2] + t8[3]);
        }
        {
            unsigned w[8];
#pragma unroll
            for (int jj = 0; jj < 8; ++jj) w[jj] = packbf2(s2[2 * jj], s2[2 * jj + 1]);
            swap32(w[0], w[2]); swap32(w[1], w[3]);
            swap32(w[4], w[6]); swap32(w[5], w[7]);
            pbs[2].u[0] = w[0]; pbs[2].u[1] = w[1]; pbs[2].u[2] = w[2]; pbs[2].u[3] = w[3];
            pbs[3].u[0] = w[4]; pbs[3].u[1] = w[5]; pbs[3].u[2] = w[6]; pbs[3].u[3] = w[7];
        }

        float ps = lpA + lpB;
        ps += __shfl_xor(ps, 32);              // identical in l, l^32
        l_run += ps;

        // ---- PV: O^T[d][q] += V^T-frag x P-frag
        __builtin_amdgcn_s_setprio(1);
#pragma unroll
        for (int c = 0; c < 4; ++c)
            o0 = __builtin_amdgcn_mfma_f32_32x32x16_bf16(vst[c], pbs[c].v, o0, 0, 0, 0);
#pragma unroll
        for (int c = 0; c < 4; ++c)
            o1 = __builtin_amdgcn_mfma_f32_32x32x16_bf16(vst[4 + c], pbs[c].v, o1, 0, 0, 0);
        __builtin_amdgcn_s_setprio(0);

        // vst consumed -> prefetch next block's V (covers next QK + softmax A)
        if (have_next) {
            const unsigned short* vj = vbase + (size_t)jn * 64;
#pragma unroll
            for (int f = 0; f < 8; ++f) vst[f] = *(const bf16x8*)(vj + voff[f]);
        }
    }

    // ---- epilogue: O[q][d] = O^T/l, d = chunk*32 + 8*s4 + 4*hi + e
    float inv = 1.0f / l_run;
    float* obase = out + qrow * Dd;
#pragma unroll
    for (int s4 = 0; s4 < 4; ++s4) {
        float4_ t0, t1;
#pragma unroll
        for (int e = 0; e < 4; ++e) { t0[e] = o0[4 * s4 + e] * inv; t1[e] = o1[4 * s4 + e] * inv; }
        *(float4_*)(obase + 8 * s4 + 4 * hi)      = t0;
        *(float4_*)(obase + 32 + 8 * s4 + 4 * hi) = t1;
    }
}

// =====================================================================
// Fallback (ws too small): round-1 proven fp32-input kernel
// =====================================================================
__global__ void attn_main(const float* __restrict__ qf, const float* __restrict__ kf,
                          const float* __restrict__ vf, const int* __restrict__ mask,
                          float* __restrict__ out) {
    int id = blockIdx.x;
    int h = id & 15, qb = id >> 4;
    int tid = threadIdx.x;
    int lane = tid & 63, wid = tid >> 6;
    int l15 = lane & 15, l4 = lane >> 4;

    __shared__ unsigned short Kl[2][64 * 64];
    __shared__ unsigned short Vl[2][64 * 64];
    __shared__ unsigned short Pl[4][16 * 64];

    const int* mrow = mask + qb * NB;
    unsigned long long b0 = __ballot(mrow[lane] != 0);
    unsigned long long b1 = __ballot(mrow[64 + lane] != 0);
    int count = __popcll(b0) + __popcll(b1);

    float* op = out + ((long)h * Nn + qb * 64 + wid * 16) * Dd;

    if (count == 0) {
#pragma unroll
        for (int r = 0; r < 4; ++r)
#pragma unroll
            for (int dn = 0; dn < 4; ++dn)
                op[(l4 * 4 + r) * Dd + dn * 16 + l15] = 0.f;
        return;
    }

    long qrow = (long)h * Nn + qb * 64 + wid * 16 + l15;
    bf16x8 qfrag[2];
#pragma unroll
    for (int dc = 0; dc < 2; ++dc) {
        const float4_* qs = (const float4_*)qf + qrow * 16 + dc * 8 + l4 * 2;
        float4_ x = qs[0], y = qs[1];
        union { unsigned short s[8]; bf16x8 v; } u;
#pragma unroll
        for (int i2 = 0; i2 < 4; ++i2) {
            u.s[i2] = f2bf(x[i2] * 0.125f);
            u.s[4 + i2] = f2bf(y[i2] * 0.125f);
        }
        qfrag[dc] = u.v;
    }

    int sgq = tid & 7;
    int srow = tid >> 3;
    float4_ kf4[2][2]; float4_ vf4[4];
    int vk = tid & 63, vd0 = (tid >> 6) * 16;

    auto load_kv = [&](int j) {
        const float4_* ks = (const float4_*)kf + ((long)h * Nn + j * 64) * 16;
#pragma unroll
        for (int it = 0; it < 2; ++it) {
            kf4[it][0] = ks[(srow + it * 32) * 16 + sgq * 2];
            kf4[it][1] = ks[(srow + it * 32) * 16 + sgq * 2 + 1];
        }
        const float4_* vs = (const float4_*)vf + ((long)h * Nn + j * 64) * 16;
#pragma unroll
        for (int c = 0; c < 4; ++c) vf4[c] = vs[vk * 16 + (vd0 >> 2) + c];
    };

    auto write_kv = [&](int buf) {
#pragma unroll
        for (int it = 0; it < 2; ++it) {
            int r = srow + it * 32;
            union { unsigned short s[8]; ushort8 v; } u;
#pragma unroll
            for (int i2 = 0; i2 < 4; ++i2) {
                u.s[i2] = f2bf(kf4[it][0][i2]);
                u.s[4 + i2] = f2bf(kf4[it][1][i2]);
            }
            *(ushort8*)((char*)&Kl[buf][0] + r * 128 + (((sgq ^ r) & 7) << 4)) = u.v;
        }
#pragma unroll
        for (int i2 = 0; i2 < 16; ++i2) {
            int d = vd0 + i2;
            *((unsigned short*)((char*)&Vl[buf][0] + d * 128 +
                ((((vk >> 3) ^ d) & 7) << 4) + ((vk & 7) << 1))) = f2bf(vf4[i2 >> 2][i2 & 3]);
        }
    };

    f32x4 o_acc[4] = {};
    float m_r[4], l_r[4];
#pragma unroll
    for (int r = 0; r < 4; ++r) { m_r[r] = -INFINITY; l_r[r] = 0.f; }

    unsigned long long r0 = b0, r1 = b1;
    auto next_j = [&]() {
        int jj;
        if (r0) { jj = __ffsll(r0) - 1; r0 &= r0 - 1; }
        else    { jj = 63 + __ffsll(r1); r1 &= r1 - 1; }
        return jj;
    };

    load_kv(next_j());

    for (int i = 0; i < count; ++i) {
        int buf = i & 1;
        write_kv(buf);
        __syncthreads();
        if (i + 1 < count) load_kv(next_j());

        f32x4 s[4] = {};
#pragma unroll
        for (int dc = 0; dc < 2; ++dc) {
#pragma unroll
            for (int kn = 0; kn < 4; ++kn) {
                int krow = kn * 16 + l15;
                bf16x8 kfr = *(const bf16x8*)((const char*)&Kl[buf][0] +
                               krow * 128 + ((((l4 + dc * 4) ^ krow) & 7) << 4));
                s[kn] = __builtin_amdgcn_mfma_f32_16x16x32_bf16(qfrag[dc], kfr, s[kn], 0, 0, 0);
            }
        }

#pragma unroll
        for (int r = 0; r < 4; ++r) {
            float mx = fmaxf(fmaxf(s[0][r], s[1][r]), fmaxf(s[2][r], s[3][r]));
#pragma unroll
            for (int off = 1; off < 16; off <<= 1) mx = fmaxf(mx, __shfl_xor(mx, off));
            float mn = fmaxf(m_r[r], mx);
            float a = __expf(m_r[r] - mn);
            m_r[r] = mn;
            float psum = 0.f;
#pragma unroll
            for (int kn = 0; kn < 4; ++kn) { float p = __expf(s[kn][r] - mn); s[kn][r] = p; psum += p; }
#pragma unroll
            for (int off = 1; off < 16; off <<= 1) psum += __shfl_xor(psum, off);
            l_r[r] = l_r[r] * a + psum;
            o_acc[0][r] *= a; o_acc[1][r] *= a; o_acc[2][r] *= a; o_acc[3][r] *= a;
        }

#pragma unroll
        for (int kn = 0; kn < 4; ++kn) {
#pragma unroll
            for (int r = 0; r < 4; ++r) {
                int prow = l4 * 4 + r;
                int pc = kn * 16 + l15;
                *((unsigned short*)((char*)&Pl[wid][0] + prow * 128 +
                    ((((pc >> 3) ^ prow) & 7) << 4) + ((pc & 7) << 1))) = f2bf(s[kn][r]);
            }
        }

        bf16x8 pa[2];
#pragma unroll
        for (int kc = 0; kc < 2; ++kc)
            pa[kc] = *(const bf16x8*)((const char*)&Pl[wid][0] +
                      l15 * 128 + ((((l4 + kc * 4) ^ l15) & 7) << 4));
#pragma unroll
        for (int dn = 0; dn < 4; ++dn) {
            int vrow = dn * 16 + l15;
#pragma unroll
            for (int kc = 0; kc < 2; ++kc) {
                bf16x8 vbf = *(const bf16x8*)((const char*)&Vl[buf][0] +
                             vrow * 128 + ((((l4 + kc * 4) ^ vrow) & 7) << 4));
                o_acc[dn] = __builtin_amdgcn_mfma_f32_16x16x32_bf16(pa[kc], vbf, o_acc[dn], 0, 0, 0);
            }
        }
    }

#pragma unroll
    for (int r = 0; r < 4; ++r) {
        float inv = 1.0f / l_r[r];
#pragma unroll
        for (int dn = 0; dn < 4; ++dn)
            op[(l4 * 4 + r) * Dd + dn * 16 + l15] = o_acc[dn][r] * inv;
    }
}

extern "C" void kernel_launch(void* const* d_in, const int* in_sizes, int n_in,
                              void* d_out, int out_size, void* d_ws, size_t ws_size,
                              hipStream_t stream) {
    const float* q = (const float*)d_in[0];
    const float* k = (const float*)d_in[1];
    const float* v = (const float*)d_in[2];
    const int* mask = (const int*)d_in[3];
    float* out = (float*)d_out;

    size_t elems = (size_t)Hh * Nn * Dd;
    size_t need = 2 * elems * sizeof(unsigned short);   // 32 MB (k16 + vt16)
    if (ws_size >= need) {
        unsigned short* k16 = (unsigned short*)d_ws;
        unsigned short* vt16 = k16 + elems;
        cvt_k<<<dim3((unsigned)(elems / 1024)), 256, 0, stream>>>(k, k16);
        cvt_vt<<<dim3(NB, Hh), 256, 0, stream>>>(v, vt16);
        attn_w<<<dim3(Hh * NB * 2), 64, 0, stream>>>(k16, vt16, q, mask, out);
    } else {
        attn_main<<<dim3(Hh * NB), 256, 0, stream>>>(q, k, v, mask, out);
    }
}

// Round 14
// 313.622 us; speedup vs baseline: 1.6813x; 1.6813x over previous
//
#include <hip/hip_runtime.h>
#include <hip/hip_bf16.h>

#define Hh 16
#define Nn 8192
#define Dd 64
#define NB 128

typedef float  f32x4   __attribute__((ext_vector_type(4)));
typedef float  f32x16  __attribute__((ext_vector_type(16)));
typedef float  float4_ __attribute__((ext_vector_type(4)));
typedef short  bf16x8  __attribute__((ext_vector_type(8)));
typedef unsigned short ushort8  __attribute__((ext_vector_type(8)));
typedef unsigned short ushort4_ __attribute__((ext_vector_type(4)));

typedef const __attribute__((address_space(1))) unsigned int gu32;
typedef __attribute__((address_space(3))) unsigned int lu32;

// log2(e) / sqrt(64) — folded into Q so QK^T lands in log2 domain
#define QSCALE 0.1803368801111244f

__device__ __forceinline__ unsigned short f2bf(float f) {
    union { float f; unsigned u; } x; x.f = f;
    unsigned r = x.u + 0x7fffu + ((x.u >> 16) & 1u);  // RNE
    return (unsigned short)(r >> 16);
}

// compiler-recognized pack: emits a single v_cvt_pk_bf16_f32 (RNE)
__device__ __forceinline__ unsigned packbf2(float lo, float hi) {
    __hip_bfloat162 h2 = __float22bfloat162_rn(make_float2(lo, hi));
    unsigned u; __builtin_memcpy(&u, &h2, 4);
    return u;
}

// ---- pre-pass 1: k -> bf16
__global__ void cvt_k(const float* __restrict__ k, unsigned short* __restrict__ ko) {
    int i = blockIdx.x * 256 + threadIdx.x;
    float4_ b = ((const float4_*)k)[i];
    ushort4_ ob;
#pragma unroll
    for (int j = 0; j < 4; ++j) ob[j] = f2bf(b[j]);
    ((ushort4_*)ko)[i] = ob;
}

// ---- pre-pass 2: v -> BLOCK-TILED vt[h][jb][d][64] bf16
// Each key block's V^T tile is a contiguous 8 KB: staging loads become
// dense 128B-stride (same shape as K), not 16KB-stride 64-line gathers.
__global__ void cvt_vt(const float* __restrict__ v, unsigned short* __restrict__ vt) {
    int jb = blockIdx.x, h = blockIdx.y, t = threadIdx.x;
    __shared__ float T[64][65];
    const float4_* src = (const float4_*)(v + ((long)h * Nn + jb * 64) * Dd);
#pragma unroll
    for (int it = 0; it < 4; ++it) {
        int r = (t >> 4) + it * 16;
        int c0 = (t & 15) * 4;
        float4_ x = src[r * 16 + (t & 15)];
#pragma unroll
        for (int i2 = 0; i2 < 4; ++i2) T[c0 + i2][r] = x[i2];
    }
    __syncthreads();
    int d = t >> 2, seg = (t & 3) * 16;
    ushort8 o0, o1;
#pragma unroll
    for (int i2 = 0; i2 < 8; ++i2) o0[i2] = f2bf(T[d][seg + i2]);
#pragma unroll
    for (int i2 = 0; i2 < 8; ++i2) o1[i2] = f2bf(T[d][seg + 8 + i2]);
    unsigned short* dst = vt + (((size_t)h * NB + jb) * Dd + d) * 64 + seg;
    *(ushort8*)dst = o0;
    *(ushort8*)(dst + 8) = o1;
}

// =====================================================================
// Main (round-11-proven structure; single change: block-tiled V^T):
// 256 threads = 4 waves covering a 128-query strip (2 mask rows).
// Waves 0,1 -> mask row A; waves 2,3 -> row B. Block iterates the UNION
// of the two rows' bitmaps; execution fully uniform, non-own blocks
// killed branchlessly by AND-masking packed P-words. l via ones-A MFMA.
// K/V via global_load_lds into fragment-major LDS, double-buffered.
// =====================================================================
__global__ __launch_bounds__(256, 4) void attn32(
        const unsigned short* __restrict__ k16,
        const unsigned short* __restrict__ vt16,
        const float* __restrict__ qf,
        const int* __restrict__ mask,
        float* __restrict__ out) {
    int bid = blockIdx.x;
    int h = (bid & 7) | ((bid >> 9) << 3);
    int qb2 = (bid >> 3) & 63;               // 128-query strip index
    int tid = threadIdx.x;
    int wid = tid >> 6, l = tid & 63;
    int q5 = l & 31, hi = l >> 5;
    int pair = wid >> 1;                     // 0: mask row A, 1: row B
    int kvrole = wid & 1;                    // 0: stages K, 1: stages V
    int half = wid >> 1;                     // which 4 fragments to stage

    __shared__ unsigned short Kl[2][4096];   // [buf] frag-major: frag*512 + lane*8 ushorts
    __shared__ unsigned short Vl[2][4096];

    const int* mrowA = mask + (qb2 * 2) * NB;
    const int* mrowB = mask + (qb2 * 2 + 1) * NB;
    unsigned long long a_lo = __ballot(mrowA[l] != 0);
    unsigned long long a_hi = __ballot(mrowA[64 + l] != 0);
    unsigned long long c_lo = __ballot(mrowB[l] != 0);
    unsigned long long c_hi = __ballot(mrowB[64 + l] != 0);
    unsigned long long u_lo = a_lo | c_lo, u_hi = a_hi | c_hi;
    int ucount = __popcll(u_lo) + __popcll(u_hi);

    if (ucount == 0) {
        float4_ z = {0.f, 0.f, 0.f, 0.f};
        float4_* ob = (float4_*)(out + ((size_t)h * Nn + qb2 * 128) * Dd);
        for (int x = tid; x < 128 * 64 / 4; x += 256) ob[x] = z;
        return;
    }

    unsigned long long own_lo = pair ? c_lo : a_lo;
    unsigned long long own_hi = pair ? c_hi : a_hi;
    int own_count = __popcll(own_lo) + __popcll(own_hi);

    // ---- Q fragments (B-operand: col=q5, k=hi*8+i within d-slice), scale folded
    size_t qrow = (size_t)h * Nn + qb2 * 128 + pair * 64 + (wid & 1) * 32 + q5;
    bf16x8 qfrag[4];
#pragma unroll
    for (int ds_ = 0; ds_ < 4; ++ds_) {
        const float4_* qs = (const float4_*)(qf + qrow * Dd + ds_ * 16 + hi * 8);
        float4_ x = qs[0], y = qs[1];
        union { unsigned u[4]; bf16x8 v; } u;
        u.u[0] = packbf2(x[0] * QSCALE, x[1] * QSCALE);
        u.u[1] = packbf2(x[2] * QSCALE, x[3] * QSCALE);
        u.u[2] = packbf2(y[0] * QSCALE, y[1] * QSCALE);
        u.u[3] = packbf2(y[2] * QSCALE, y[3] * QSCALE);
        qfrag[ds_] = u.v;
    }

    // ---- ones A-fragment for the l-sum MFMA (layout-proof)
    union { unsigned short s[8]; bf16x8 v; } ones;
#pragma unroll
    for (int i2 = 0; i2 < 8; ++i2) ones.s[i2] = 0x3F80;  // bf16 1.0

    // ---- per-lane staging source pointers for this wave's 4 fragments
    // K  frag f: key (q5+32*(f>>2)), d-slice (f&3)  — dense 128B-stride tile
    // V^T frag f: d-row (q5+32*(f>>2)), key-slice (f&3) — NOW dense (tiled)
    const unsigned short* sp[4];
#pragma unroll
    for (int ff = 0; ff < 4; ++ff) {
        int f = half * 4 + ff;
        if (kvrole == 0)
            sp[ff] = k16 + (size_t)h * (Nn * Dd)
                   + (size_t)(q5 + 32 * (f >> 2)) * Dd + (f & 3) * 16 + hi * 8;
        else
            sp[ff] = vt16 + (size_t)h * (Nn * Dd)
                   + (size_t)(q5 + 32 * (f >> 2)) * 64 + (f & 3) * 16 + hi * 8;
    }
    const int jmul = 64 * Dd;   // both K and tiled V^T advance 4096 elems/block

    unsigned long long r0 = u_lo, r1 = u_hi;
    auto next_j = [&]() {
        int jj;
        if (r0) { jj = __ffsll(r0) - 1; r0 &= r0 - 1; }
        else    { jj = 63 + __ffsll(r1); r1 &= r1 - 1; }
        return jj;
    };

    auto issue = [&](int nbuf, int jj) {
        unsigned short* lb = (kvrole == 0) ? &Kl[nbuf][0] : &Vl[nbuf][0];
#pragma unroll
        for (int ff = 0; ff < 4; ++ff) {
            const unsigned short* g = sp[ff] + (size_t)jj * jmul;
            __builtin_amdgcn_global_load_lds((gu32*)g,
                (lu32*)(lb + (half * 4 + ff) * 512), 16, 0, 0);
        }
    };

    int jcur = next_j();
    issue(0, jcur);

    f32x16 o0 = {}, o1 = {}, ls = {};

    for (int i = 0; i < ucount; ++i) {
        int buf = i & 1;
        __syncthreads();                       // drains prefetch + orders buffer reuse
        int jnext = 0;
        if (i + 1 < ucount) { jnext = next_j(); issue(buf ^ 1, jnext); }

        bool act = (jcur < 64) ? ((own_lo >> jcur) & 1ull)
                               : ((own_hi >> (jcur - 64)) & 1ull);
        unsigned msk = act ? 0xFFFFFFFFu : 0u; // wave-uniform, branchless kill
        jcur = jnext;

        const char* kb = (const char*)Kl + buf * 8192 + l * 16;
        const char* vb = (const char*)Vl + buf * 8192 + l * 16;

        // ---- QK^T: S^T[key][q] in log2 domain; s0 = keys 0..31, s1 = keys 32..63
        f32x16 s0 = {}, s1 = {};
#pragma unroll
        for (int ds_ = 0; ds_ < 4; ++ds_) {
            bf16x8 kf0 = *(const bf16x8*)(kb + ds_ * 1024);
            s0 = __builtin_amdgcn_mfma_f32_32x32x16_bf16(kf0, qfrag[ds_], s0, 0, 0, 0);
        }
#pragma unroll
        for (int ds_ = 0; ds_ < 4; ++ds_) {
            bf16x8 kf1 = *(const bf16x8*)(kb + 4096 + ds_ * 1024);
            s1 = __builtin_amdgcn_mfma_f32_32x32x16_bf16(kf1, qfrag[ds_], s1, 0, 0, 0);
        }

        // ---- P = 2^S (compiler-emitted v_exp_f32; hazard-safe)
#pragma unroll
        for (int e = 0; e < 16; ++e) s0[e] = __builtin_amdgcn_exp2f(s0[e]);
#pragma unroll
        for (int e = 0; e < 16; ++e) s1[e] = __builtin_amdgcn_exp2f(s1[e]);

        // ---- P -> bf16 B-fragments (single cvt_pk each); non-own AND-masked to 0
        unsigned w0[8], w1[8];
#pragma unroll
        for (int jj = 0; jj < 8; ++jj) {
            w0[jj] = packbf2(s0[2 * jj], s0[2 * jj + 1]) & msk;
            w1[jj] = packbf2(s1[2 * jj], s1[2 * jj + 1]) & msk;
        }
        auto swap32 = [&](unsigned& a, unsigned& b) {
            unsigned send = hi ? a : b;
            unsigned recv = (unsigned)__shfl_xor((int)send, 32);
            a = hi ? recv : a;
            b = hi ? b : recv;
        };
        swap32(w0[0], w0[2]); swap32(w0[1], w0[3]);
        swap32(w0[4], w0[6]); swap32(w0[5], w0[7]);
        swap32(w1[0], w1[2]); swap32(w1[1], w1[3]);
        swap32(w1[4], w1[6]); swap32(w1[5], w1[7]);

        union U { unsigned u[4]; bf16x8 v; };
        U pbs[4];
        pbs[0].u[0] = w0[0]; pbs[0].u[1] = w0[1]; pbs[0].u[2] = w0[2]; pbs[0].u[3] = w0[3];
        pbs[1].u[0] = w0[4]; pbs[1].u[1] = w0[5]; pbs[1].u[2] = w0[6]; pbs[1].u[3] = w0[7];
        pbs[2].u[0] = w1[0]; pbs[2].u[1] = w1[1]; pbs[2].u[2] = w1[2]; pbs[2].u[3] = w1[3];
        pbs[3].u[0] = w1[4]; pbs[3].u[1] = w1[5]; pbs[3].u[2] = w1[6]; pbs[3].u[3] = w1[7];

        // ---- PV: O^T[d][q] += V^T-frag x P-frag
#pragma unroll
        for (int c = 0; c < 4; ++c) {
            bf16x8 vf0 = *(const bf16x8*)(vb + c * 1024);
            o0 = __builtin_amdgcn_mfma_f32_32x32x16_bf16(vf0, pbs[c].v, o0, 0, 0, 0);
        }
#pragma unroll
        for (int c = 0; c < 4; ++c) {
            bf16x8 vf1 = *(const bf16x8*)(vb + 4096 + c * 1024);
            o1 = __builtin_amdgcn_mfma_f32_32x32x16_bf16(vf1, pbs[c].v, o1, 0, 0, 0);
        }
        // ---- l on the MFMA pipe: ls += colsum(P)
#pragma unroll
        for (int c = 0; c < 4; ++c)
            ls = __builtin_amdgcn_mfma_f32_32x32x16_bf16(ones.v, pbs[c].v, ls, 0, 0, 0);
    }

    // ---- epilogue: O[q][d] = O^T/l, d = dchunk*32 + 8*s4 + 4*hi + e
    float inv = own_count ? (1.0f / ls[0]) : 0.f;
    float* obase = out + qrow * Dd;
#pragma unroll
    for (int s4 = 0; s4 < 4; ++s4) {
        float4_ t0, t1;
#pragma unroll
        for (int e = 0; e < 4; ++e) { t0[e] = o0[4 * s4 + e] * inv; t1[e] = o1[4 * s4 + e] * inv; }
        *(float4_*)(obase + 8 * s4 + 4 * hi)      = t0;
        *(float4_*)(obase + 32 + 8 * s4 + 4 * hi) = t1;
    }
}

// =====================================================================
// Fallback (ws too small): round-1 proven fp32-input kernel
// =====================================================================
__global__ void attn_main(const float* __restrict__ qf, const float* __restrict__ kf,
                          const float* __restrict__ vf, const int* __restrict__ mask,
                          float* __restrict__ out) {
    int id = blockIdx.x;
    int h = id & 15, qb = id >> 4;
    int tid = threadIdx.x;
    int lane = tid & 63, wid = tid >> 6;
    int l15 = lane & 15, l4 = lane >> 4;

    __shared__ unsigned short Kl[2][64 * 64];
    __shared__ unsigned short Vl[2][64 * 64];
    __shared__ unsigned short Pl[4][16 * 64];

    const int* mrow = mask + qb * NB;
    unsigned long long b0 = __ballot(mrow[lane] != 0);
    unsigned long long b1 = __ballot(mrow[64 + lane] != 0);
    int count = __popcll(b0) + __popcll(b1);

    float* op = out + ((long)h * Nn + qb * 64 + wid * 16) * Dd;

    if (count == 0) {
#pragma unroll
        for (int r = 0; r < 4; ++r)
#pragma unroll
            for (int dn = 0; dn < 4; ++dn)
                op[(l4 * 4 + r) * Dd + dn * 16 + l15] = 0.f;
        return;
    }

    long qrow = (long)h * Nn + qb * 64 + wid * 16 + l15;
    bf16x8 qfrag[2];
#pragma unroll
    for (int dc = 0; dc < 2; ++dc) {
        const float4_* qs = (const float4_*)qf + qrow * 16 + dc * 8 + l4 * 2;
        float4_ x = qs[0], y = qs[1];
        union { unsigned short s[8]; bf16x8 v; } u;
#pragma unroll
        for (int i2 = 0; i2 < 4; ++i2) {
            u.s[i2] = f2bf(x[i2] * 0.125f);
            u.s[4 + i2] = f2bf(y[i2] * 0.125f);
        }
        qfrag[dc] = u.v;
    }

    int sgq = tid & 7;
    int srow = tid >> 3;
    float4_ kf4[2][2]; float4_ vf4[4];
    int vk = tid & 63, vd0 = (tid >> 6) * 16;

    auto load_kv = [&](int j) {
        const float4_* ks = (const float4_*)kf + ((long)h * Nn + j * 64) * 16;
#pragma unroll
        for (int it = 0; it < 2; ++it) {
            kf4[it][0] = ks[(srow + it * 32) * 16 + sgq * 2];
            kf4[it][1] = ks[(srow + it * 32) * 16 + sgq * 2 + 1];
        }
        const float4_* vs = (const float4_*)vf + ((long)h * Nn + j * 64) * 16;
#pragma unroll
        for (int c = 0; c < 4; ++c) vf4[c] = vs[vk * 16 + (vd0 >> 2) + c];
    };

    auto write_kv = [&](int buf) {
#pragma unroll
        for (int it = 0; it < 2; ++it) {
            int r = srow + it * 32;
            union { unsigned short s[8]; ushort8 v; } u;
#pragma unroll
            for (int i2 = 0; i2 < 4; ++i2) {
                u.s[i2] = f2bf(kf4[it][0][i2]);
                u.s[4 + i2] = f2bf(kf4[it][1][i2]);
            }
            *(ushort8*)((char*)&Kl[buf][0] + r * 128 + (((sgq ^ r) & 7) << 4)) = u.v;
        }
#pragma unroll
        for (int i2 = 0; i2 < 16; ++i2) {
            int d = vd0 + i2;
            *((unsigned short*)((char*)&Vl[buf][0] + d * 128 +
                ((((vk >> 3) ^ d) & 7) << 4) + ((vk & 7) << 1))) = f2bf(vf4[i2 >> 2][i2 & 3]);
        }
    };

    f32x4 o_acc[4] = {};
    float m_r[4], l_r[4];
#pragma unroll
    for (int r = 0; r < 4; ++r) { m_r[r] = -INFINITY; l_r[r] = 0.f; }

    unsigned long long r0 = b0, r1 = b1;
    auto next_j = [&]() {
        int jj;
        if (r0) { jj = __ffsll(r0) - 1; r0 &= r0 - 1; }
        else    { jj = 63 + __ffsll(r1); r1 &= r1 - 1; }
        return jj;
    };

    load_kv(next_j());

    for (int i = 0; i < count; ++i) {
        int buf = i & 1;
        write_kv(buf);
        __syncthreads();
        if (i + 1 < count) load_kv(next_j());

        f32x4 s[4] = {};
#pragma unroll
        for (int dc = 0; dc < 2; ++dc) {
#pragma unroll
            for (int kn = 0; kn < 4; ++kn) {
                int krow = kn * 16 + l15;
                bf16x8 kfr = *(const bf16x8*)((const char*)&Kl[buf][0] +
                               krow * 128 + ((((l4 + dc * 4) ^ krow) & 7) << 4));
                s[kn] = __builtin_amdgcn_mfma_f32_16x16x32_bf16(qfrag[dc], kfr, s[kn], 0, 0, 0);
            }
        }

#pragma unroll
        for (int r = 0; r < 4; ++r) {
            float mx = fmaxf(fmaxf(s[0][r], s[1][r]), fmaxf(s[2][r], s[3][r]));
#pragma unroll
            for (int off = 1; off < 16; off <<= 1) mx = fmaxf(mx, __shfl_xor(mx, off));
            float mn = fmaxf(m_r[r], mx);
            float a = __expf(m_r[r] - mn);
            m_r[r] = mn;
            float psum = 0.f;
#pragma unroll
            for (int kn = 0; kn < 4; ++kn) { float p = __expf(s[kn][r] - mn); s[kn][r] = p; psum += p; }
#pragma unroll
            for (int off = 1; off < 16; off <<= 1) psum += __shfl_xor(psum, off);
            l_r[r] = l_r[r] * a + psum;
            o_acc[0][r] *= a; o_acc[1][r] *= a; o_acc[2][r] *= a; o_acc[3][r] *= a;
        }

#pragma unroll
        for (int kn = 0; kn < 4; ++kn) {
#pragma unroll
            for (int r = 0; r < 4; ++r) {
                int prow = l4 * 4 + r;
                int pc = kn * 16 + l15;
                *((unsigned short*)((char*)&Pl[wid][0] + prow * 128 +
                    ((((pc >> 3) ^ prow) & 7) << 4) + ((pc & 7) << 1))) = f2bf(s[kn][r]);
            }
        }

        bf16x8 pa[2];
#pragma unroll
        for (int kc = 0; kc < 2; ++kc)
            pa[kc] = *(const bf16x8*)((const char*)&Pl[wid][0] +
                      l15 * 128 + ((((l4 + kc * 4) ^ l15) & 7) << 4));
#pragma unroll
        for (int dn = 0; dn < 4; ++dn) {
            int vrow = dn * 16 + l15;
#pragma unroll
            for (int kc = 0; kc < 2; ++kc) {
                bf16x8 vbf = *(const bf16x8*)((const char*)&Vl[buf][0] +
                             vrow * 128 + ((((l4 + kc * 4) ^ vrow) & 7) << 4));
                o_acc[dn] = __builtin_amdgcn_mfma_f32_16x16x32_bf16(pa[kc], vbf, o_acc[dn], 0, 0, 0);
            }
        }
    }

#pragma unroll
    for (int r = 0; r < 4; ++r) {
        float inv = 1.0f / l_r[r];
#pragma unroll
        for (int dn = 0; dn < 4; ++dn)
            op[(l4 * 4 + r) * Dd + dn * 16 + l15] = o_acc[dn][r] * inv;
    }
}

extern "C" void kernel_launch(void* const* d_in, const int* in_sizes, int n_in,
                              void* d_out, int out_size, void* d_ws, size_t ws_size,
                              hipStream_t stream) {
    const float* q = (const float*)d_in[0];
    const float* k = (const float*)d_in[1];
    const float* v = (const float*)d_in[2];
    const int* mask = (const int*)d_in[3];
    float* out = (float*)d_out;

    size_t elems = (size_t)Hh * Nn * Dd;
    size_t need = 2 * elems * sizeof(unsigned short);   // 32 MB (k16 + vt16)
    if (ws_size >= need) {
        unsigned short* k16 = (unsigned short*)d_ws;
        unsigned short* vt16 = k16 + elems;
        cvt_k<<<dim3((unsigned)(elems / 1024)), 256, 0, stream>>>(k, k16);
        cvt_vt<<<dim3(NB, Hh), 256, 0, stream>>>(v, vt16);
        attn32<<<dim3(Hh * NB / 2), 256, 0, stream>>>(k16, vt16, q, mask, out);
    } else {
        attn_main<<<dim3(Hh * NB), 256, 0, stream>>>(q, k, v, mask, out);
    }
}

// Round 15
// 288.551 us; speedup vs baseline: 1.8274x; 1.0869x over previous
//
#include <hip/hip_runtime.h>
#include <hip/hip_bf16.h>

#define Hh 16
#define Nn 8192
#define Dd 64
#define NB 128

typedef float  f32x4   __attribute__((ext_vector_type(4)));
typedef float  f32x16  __attribute__((ext_vector_type(16)));
typedef float  float4_ __attribute__((ext_vector_type(4)));
typedef short  bf16x8  __attribute__((ext_vector_type(8)));
typedef unsigned short ushort8  __attribute__((ext_vector_type(8)));
typedef unsigned short ushort4_ __attribute__((ext_vector_type(4)));

typedef const __attribute__((address_space(1))) unsigned int gu32;
typedef __attribute__((address_space(3))) unsigned int lu32;

// log2(e) / sqrt(64) — folded into Q so QK^T lands in log2 domain
#define QSCALE 0.1803368801111244f

__device__ __forceinline__ unsigned short f2bf(float f) {
    union { float f; unsigned u; } x; x.f = f;
    unsigned r = x.u + 0x7fffu + ((x.u >> 16) & 1u);  // RNE
    return (unsigned short)(r >> 16);
}

// compiler-recognized pack: emits a single v_cvt_pk_bf16_f32 (RNE)
__device__ __forceinline__ unsigned packbf2(float lo, float hi) {
    __hip_bfloat162 h2 = __float22bfloat162_rn(make_float2(lo, hi));
    unsigned u; __builtin_memcpy(&u, &h2, 4);
    return u;
}

// ---- pre-pass 1: k -> bf16
__global__ void cvt_k(const float* __restrict__ k, unsigned short* __restrict__ ko) {
    int i = blockIdx.x * 256 + threadIdx.x;
    float4_ b = ((const float4_*)k)[i];
    ushort4_ ob;
#pragma unroll
    for (int j = 0; j < 4; ++j) ob[j] = f2bf(b[j]);
    ((ushort4_*)ko)[i] = ob;
}

// ---- pre-pass 2: v -> BLOCK-TILED vt[h][jb][d][64] bf16 (dense 8KB tiles)
__global__ void cvt_vt(const float* __restrict__ v, unsigned short* __restrict__ vt) {
    int jb = blockIdx.x, h = blockIdx.y, t = threadIdx.x;
    __shared__ float T[64][65];
    const float4_* src = (const float4_*)(v + ((long)h * Nn + jb * 64) * Dd);
#pragma unroll
    for (int it = 0; it < 4; ++it) {
        int r = (t >> 4) + it * 16;
        int c0 = (t & 15) * 4;
        float4_ x = src[r * 16 + (t & 15)];
#pragma unroll
        for (int i2 = 0; i2 < 4; ++i2) T[c0 + i2][r] = x[i2];
    }
    __syncthreads();
    int d = t >> 2, seg = (t & 3) * 16;
    ushort8 o0, o1;
#pragma unroll
    for (int i2 = 0; i2 < 8; ++i2) o0[i2] = f2bf(T[d][seg + i2]);
#pragma unroll
    for (int i2 = 0; i2 < 8; ++i2) o1[i2] = f2bf(T[d][seg + 8 + i2]);
    unsigned short* dst = vt + (((size_t)h * NB + jb) * Dd + d) * 64 + seg;
    *(ushort8*)dst = o0;
    *(ushort8*)(dst + 8) = o1;
}

// =====================================================================
// Main: 256 threads = 4 waves, 128-query strip (2 mask rows), but each
// wave-PAIR has its OWN private K/V double-buffer and iterates its OWN
// row's bitmap (no union waste). Loop bound = max(cntA,cntB): every
// wave executes every iteration (uniform CFG, uniform barriers); a pair
// past its own count processes dummy j=0 tiles killed by the r11-proven
// AND-mask (~4 iters avg). Wave (pair,qh): computes row `pair`, queries
// qh*32..; stages pair's K (qh=0) or V (qh=1), 8 frags (r5 pattern).
// Inner loop identical to r11/r14. l via ones-A MFMA. LDS 64 KB.
// =====================================================================
__global__ __launch_bounds__(256, 2) void attn32(
        const unsigned short* __restrict__ k16,
        const unsigned short* __restrict__ vt16,
        const float* __restrict__ qf,
        const int* __restrict__ mask,
        float* __restrict__ out) {
    int bid = blockIdx.x;
    int h = (bid & 7) | ((bid >> 9) << 3);
    int qb2 = (bid >> 3) & 63;               // 128-query strip index
    int tid = threadIdx.x;
    int wid = tid >> 6, l = tid & 63;
    int q5 = l & 31, hi = l >> 5;
    int pair = wid >> 1;                     // mask row A (0) / B (1); also LDS region
    int kvrole = wid & 1;                    // 0: stages pair's K, 1: stages pair's V

    __shared__ unsigned short Kl[2][2][4096];   // [pair][buf] frag-major
    __shared__ unsigned short Vl[2][2][4096];

    const int* mrowA = mask + (qb2 * 2) * NB;
    const int* mrowB = mask + (qb2 * 2 + 1) * NB;
    unsigned long long a_lo = __ballot(mrowA[l] != 0);
    unsigned long long a_hi = __ballot(mrowA[64 + l] != 0);
    unsigned long long c_lo = __ballot(mrowB[l] != 0);
    unsigned long long c_hi = __ballot(mrowB[64 + l] != 0);
    int cntA = __popcll(a_lo) + __popcll(a_hi);
    int cntB = __popcll(c_lo) + __popcll(c_hi);
    int maxcnt = cntA > cntB ? cntA : cntB;

    if (maxcnt == 0) {
        float4_ z = {0.f, 0.f, 0.f, 0.f};
        float4_* ob = (float4_*)(out + ((size_t)h * Nn + qb2 * 128) * Dd);
        for (int x = tid; x < 128 * 64 / 4; x += 256) ob[x] = z;
        return;
    }

    int cnt_own = pair ? cntB : cntA;
    unsigned long long r0 = pair ? c_lo : a_lo;
    unsigned long long r1 = pair ? c_hi : a_hi;

    // ---- Q fragments (B-operand: col=q5, k=hi*8+i within d-slice), scale folded
    size_t qrow = (size_t)h * Nn + qb2 * 128 + pair * 64 + kvrole * 32 + q5;
    bf16x8 qfrag[4];
#pragma unroll
    for (int ds_ = 0; ds_ < 4; ++ds_) {
        const float4_* qs = (const float4_*)(qf + qrow * Dd + ds_ * 16 + hi * 8);
        float4_ x = qs[0], y = qs[1];
        union { unsigned u[4]; bf16x8 v; } u;
        u.u[0] = packbf2(x[0] * QSCALE, x[1] * QSCALE);
        u.u[1] = packbf2(x[2] * QSCALE, x[3] * QSCALE);
        u.u[2] = packbf2(y[0] * QSCALE, y[1] * QSCALE);
        u.u[3] = packbf2(y[2] * QSCALE, y[3] * QSCALE);
        qfrag[ds_] = u.v;
    }

    // ---- ones A-fragment for the l-sum MFMA (layout-proof)
    union { unsigned short s[8]; bf16x8 v; } ones;
#pragma unroll
    for (int i2 = 0; i2 < 8; ++i2) ones.s[i2] = 0x3F80;  // bf16 1.0

    // ---- staging source pointers: this wave stages ALL 8 frags of its
    // pair's K (kvrole=0) or tiled V^T (kvrole=1); both dense 8KB tiles.
    const unsigned short* sp[8];
#pragma unroll
    for (int f = 0; f < 8; ++f) {
        if (kvrole == 0)
            sp[f] = k16 + (size_t)h * (Nn * Dd)
                  + (size_t)(q5 + 32 * (f >> 2)) * Dd + (f & 3) * 16 + hi * 8;
        else
            sp[f] = vt16 + (size_t)h * (Nn * Dd)
                  + (size_t)(q5 + 32 * (f >> 2)) * 64 + (f & 3) * 16 + hi * 8;
    }
    const int jmul = 64 * Dd;   // both K and tiled V^T advance 4096 elems/block

    auto next_j = [&]() {
        int jj;
        if (r0)      { jj = __ffsll(r0) - 1; r0 &= r0 - 1; }
        else if (r1) { jj = 63 + __ffsll(r1); r1 &= r1 - 1; }
        else         { jj = 0; }             // exhausted: dummy tile (masked)
        return jj;
    };

    auto issue = [&](int nbuf, int jj) {
        unsigned short* lb = (kvrole == 0) ? &Kl[pair][nbuf][0] : &Vl[pair][nbuf][0];
#pragma unroll
        for (int f = 0; f < 8; ++f) {
            const unsigned short* g = sp[f] + (size_t)jj * jmul;
            __builtin_amdgcn_global_load_lds((gu32*)g, (lu32*)(lb + f * 512), 16, 0, 0);
        }
    };

    issue(0, next_j());

    f32x16 o0 = {}, o1 = {}, ls = {};

    for (int i = 0; i < maxcnt; ++i) {
        int buf = i & 1;
        __syncthreads();                       // uniform: drains prefetch, orders reuse
        if (i + 1 < maxcnt) issue(buf ^ 1, next_j());

        unsigned msk = (i < cnt_own) ? 0xFFFFFFFFu : 0u;  // wave-uniform tail kill

        const char* kb = (const char*)&Kl[pair][buf][0] + l * 16;
        const char* vb = (const char*)&Vl[pair][buf][0] + l * 16;

        // ---- QK^T: S^T[key][q] in log2 domain; s0 = keys 0..31, s1 = keys 32..63
        f32x16 s0 = {}, s1 = {};
#pragma unroll
        for (int ds_ = 0; ds_ < 4; ++ds_) {
            bf16x8 kf0 = *(const bf16x8*)(kb + ds_ * 1024);
            s0 = __builtin_amdgcn_mfma_f32_32x32x16_bf16(kf0, qfrag[ds_], s0, 0, 0, 0);
        }
#pragma unroll
        for (int ds_ = 0; ds_ < 4; ++ds_) {
            bf16x8 kf1 = *(const bf16x8*)(kb + 4096 + ds_ * 1024);
            s1 = __builtin_amdgcn_mfma_f32_32x32x16_bf16(kf1, qfrag[ds_], s1, 0, 0, 0);
        }

        // ---- P = 2^S (compiler-emitted v_exp_f32; hazard-safe)
#pragma unroll
        for (int e = 0; e < 16; ++e) s0[e] = __builtin_amdgcn_exp2f(s0[e]);
#pragma unroll
        for (int e = 0; e < 16; ++e) s1[e] = __builtin_amdgcn_exp2f(s1[e]);

        // ---- P -> bf16 B-fragments (single cvt_pk each); tail iters masked to 0
        unsigned w0[8], w1[8];
#pragma unroll
        for (int jj = 0; jj < 8; ++jj) {
            w0[jj] = packbf2(s0[2 * jj], s0[2 * jj + 1]) & msk;
            w1[jj] = packbf2(s1[2 * jj], s1[2 * jj + 1]) & msk;
        }
        auto swap32 = [&](unsigned& a, unsigned& b) {
            unsigned send = hi ? a : b;
            unsigned recv = (unsigned)__shfl_xor((int)send, 32);
            a = hi ? recv : a;
            b = hi ? b : recv;
        };
        swap32(w0[0], w0[2]); swap32(w0[1], w0[3]);
        swap32(w0[4], w0[6]); swap32(w0[5], w0[7]);
        swap32(w1[0], w1[2]); swap32(w1[1], w1[3]);
        swap32(w1[4], w1[6]); swap32(w1[5], w1[7]);

        union U { unsigned u[4]; bf16x8 v; };
        U pbs[4];
        pbs[0].u[0] = w0[0]; pbs[0].u[1] = w0[1]; pbs[0].u[2] = w0[2]; pbs[0].u[3] = w0[3];
        pbs[1].u[0] = w0[4]; pbs[1].u[1] = w0[5]; pbs[1].u[2] = w0[6]; pbs[1].u[3] = w0[7];
        pbs[2].u[0] = w1[0]; pbs[2].u[1] = w1[1]; pbs[2].u[2] = w1[2]; pbs[2].u[3] = w1[3];
        pbs[3].u[0] = w1[4]; pbs[3].u[1] = w1[5]; pbs[3].u[2] = w1[6]; pbs[3].u[3] = w1[7];

        // ---- PV: O^T[d][q] += V^T-frag x P-frag
#pragma unroll
        for (int c = 0; c < 4; ++c) {
            bf16x8 vf0 = *(const bf16x8*)(vb + c * 1024);
            o0 = __builtin_amdgcn_mfma_f32_32x32x16_bf16(vf0, pbs[c].v, o0, 0, 0, 0);
        }
#pragma unroll
        for (int c = 0; c < 4; ++c) {
            bf16x8 vf1 = *(const bf16x8*)(vb + 4096 + c * 1024);
            o1 = __builtin_amdgcn_mfma_f32_32x32x16_bf16(vf1, pbs[c].v, o1, 0, 0, 0);
        }
        // ---- l on the MFMA pipe: ls += colsum(P)
#pragma unroll
        for (int c = 0; c < 4; ++c)
            ls = __builtin_amdgcn_mfma_f32_32x32x16_bf16(ones.v, pbs[c].v, ls, 0, 0, 0);
    }

    // ---- epilogue: O[q][d] = O^T/l, d = dchunk*32 + 8*s4 + 4*hi + e
    float inv = cnt_own ? (1.0f / ls[0]) : 0.f;
    float* obase = out + qrow * Dd;
#pragma unroll
    for (int s4 = 0; s4 < 4; ++s4) {
        float4_ t0, t1;
#pragma unroll
        for (int e = 0; e < 4; ++e) { t0[e] = o0[4 * s4 + e] * inv; t1[e] = o1[4 * s4 + e] * inv; }
        *(float4_*)(obase + 8 * s4 + 4 * hi)      = t0;
        *(float4_*)(obase + 32 + 8 * s4 + 4 * hi) = t1;
    }
}

// =====================================================================
// Fallback (ws too small): round-1 proven fp32-input kernel
// =====================================================================
__global__ void attn_main(const float* __restrict__ qf, const float* __restrict__ kf,
                          const float* __restrict__ vf, const int* __restrict__ mask,
                          float* __restrict__ out) {
    int id = blockIdx.x;
    int h = id & 15, qb = id >> 4;
    int tid = threadIdx.x;
    int lane = tid & 63, wid = tid >> 6;
    int l15 = lane & 15, l4 = lane >> 4;

    __shared__ unsigned short Kl[2][64 * 64];
    __shared__ unsigned short Vl[2][64 * 64];
    __shared__ unsigned short Pl[4][16 * 64];

    const int* mrow = mask + qb * NB;
    unsigned long long b0 = __ballot(mrow[lane] != 0);
    unsigned long long b1 = __ballot(mrow[64 + lane] != 0);
    int count = __popcll(b0) + __popcll(b1);

    float* op = out + ((long)h * Nn + qb * 64 + wid * 16) * Dd;

    if (count == 0) {
#pragma unroll
        for (int r = 0; r < 4; ++r)
#pragma unroll
            for (int dn = 0; dn < 4; ++dn)
                op[(l4 * 4 + r) * Dd + dn * 16 + l15] = 0.f;
        return;
    }

    long qrow = (long)h * Nn + qb * 64 + wid * 16 + l15;
    bf16x8 qfrag[2];
#pragma unroll
    for (int dc = 0; dc < 2; ++dc) {
        const float4_* qs = (const float4_*)qf + qrow * 16 + dc * 8 + l4 * 2;
        float4_ x = qs[0], y = qs[1];
        union { unsigned short s[8]; bf16x8 v; } u;
#pragma unroll
        for (int i2 = 0; i2 < 4; ++i2) {
            u.s[i2] = f2bf(x[i2] * 0.125f);
            u.s[4 + i2] = f2bf(y[i2] * 0.125f);
        }
        qfrag[dc] = u.v;
    }

    int sgq = tid & 7;
    int srow = tid >> 3;
    float4_ kf4[2][2]; float4_ vf4[4];
    int vk = tid & 63, vd0 = (tid >> 6) * 16;

    auto load_kv = [&](int j) {
        const float4_* ks = (const float4_*)kf + ((long)h * Nn + j * 64) * 16;
#pragma unroll
        for (int it = 0; it < 2; ++it) {
            kf4[it][0] = ks[(srow + it * 32) * 16 + sgq * 2];
            kf4[it][1] = ks[(srow + it * 32) * 16 + sgq * 2 + 1];
        }
        const float4_* vs = (const float4_*)vf + ((long)h * Nn + j * 64) * 16;
#pragma unroll
        for (int c = 0; c < 4; ++c) vf4[c] = vs[vk * 16 + (vd0 >> 2) + c];
    };

    auto write_kv = [&](int buf) {
#pragma unroll
        for (int it = 0; it < 2; ++it) {
            int r = srow + it * 32;
            union { unsigned short s[8]; ushort8 v; } u;
#pragma unroll
            for (int i2 = 0; i2 < 4; ++i2) {
                u.s[i2] = f2bf(kf4[it][0][i2]);
                u.s[4 + i2] = f2bf(kf4[it][1][i2]);
            }
            *(ushort8*)((char*)&Kl[buf][0] + r * 128 + (((sgq ^ r) & 7) << 4)) = u.v;
        }
#pragma unroll
        for (int i2 = 0; i2 < 16; ++i2) {
            int d = vd0 + i2;
            *((unsigned short*)((char*)&Vl[buf][0] + d * 128 +
                ((((vk >> 3) ^ d) & 7) << 4) + ((vk & 7) << 1))) = f2bf(vf4[i2 >> 2][i2 & 3]);
        }
    };

    f32x4 o_acc[4] = {};
    float m_r[4], l_r[4];
#pragma unroll
    for (int r = 0; r < 4; ++r) { m_r[r] = -INFINITY; l_r[r] = 0.f; }

    unsigned long long r0 = b0, r1 = b1;
    auto next_j = [&]() {
        int jj;
        if (r0) { jj = __ffsll(r0) - 1; r0 &= r0 - 1; }
        else    { jj = 63 + __ffsll(r1); r1 &= r1 - 1; }
        return jj;
    };

    load_kv(next_j());

    for (int i = 0; i < count; ++i) {
        int buf = i & 1;
        write_kv(buf);
        __syncthreads();
        if (i + 1 < count) load_kv(next_j());

        f32x4 s[4] = {};
#pragma unroll
        for (int dc = 0; dc < 2; ++dc) {
#pragma unroll
            for (int kn = 0; kn < 4; ++kn) {
                int krow = kn * 16 + l15;
                bf16x8 kfr = *(const bf16x8*)((const char*)&Kl[buf][0] +
                               krow * 128 + ((((l4 + dc * 4) ^ krow) & 7) << 4));
                s[kn] = __builtin_amdgcn_mfma_f32_16x16x32_bf16(qfrag[dc], kfr, s[kn], 0, 0, 0);
            }
        }

#pragma unroll
        for (int r = 0; r < 4; ++r) {
            float mx = fmaxf(fmaxf(s[0][r], s[1][r]), fmaxf(s[2][r], s[3][r]));
#pragma unroll
            for (int off = 1; off < 16; off <<= 1) mx = fmaxf(mx, __shfl_xor(mx, off));
            float mn = fmaxf(m_r[r], mx);
            float a = __expf(m_r[r] - mn);
            m_r[r] = mn;
            float psum = 0.f;
#pragma unroll
            for (int kn = 0; kn < 4; ++kn) { float p = __expf(s[kn][r] - mn); s[kn][r] = p; psum += p; }
#pragma unroll
            for (int off = 1; off < 16; off <<= 1) psum += __shfl_xor(psum, off);
            l_r[r] = l_r[r] * a + psum;
            o_acc[0][r] *= a; o_acc[1][r] *= a; o_acc[2][r] *= a; o_acc[3][r] *= a;
        }

#pragma unroll
        for (int kn = 0; kn < 4; ++kn) {
#pragma unroll
            for (int r = 0; r < 4; ++r) {
                int prow = l4 * 4 + r;
                int pc = kn * 16 + l15;
                *((unsigned short*)((char*)&Pl[wid][0] + prow * 128 +
                    ((((pc >> 3) ^ prow) & 7) << 4) + ((pc & 7) << 1))) = f2bf(s[kn][r]);
            }
        }

        bf16x8 pa[2];
#pragma unroll
        for (int kc = 0; kc < 2; ++kc)
            pa[kc] = *(const bf16x8*)((const char*)&Pl[wid][0] +
                      l15 * 128 + ((((l4 + kc * 4) ^ l15) & 7) << 4));
#pragma unroll
        for (int dn = 0; dn < 4; ++dn) {
            int vrow = dn * 16 + l15;
#pragma unroll
            for (int kc = 0; kc < 2; ++kc) {
                bf16x8 vbf = *(const bf16x8*)((const char*)&Vl[buf][0] +
                             vrow * 128 + ((((l4 + kc * 4) ^ vrow) & 7) << 4));
                o_acc[dn] = __builtin_amdgcn_mfma_f32_16x16x32_bf16(pa[kc], vbf, o_acc[dn], 0, 0, 0);
            }
        }
    }

#pragma unroll
    for (int r = 0; r < 4; ++r) {
        float inv = 1.0f / l_r[r];
#pragma unroll
        for (int dn = 0; dn < 4; ++dn)
            op[(l4 * 4 + r) * Dd + dn * 16 + l15] = o_acc[dn][r] * inv;
    }
}

extern "C" void kernel_launch(void* const* d_in, const int* in_sizes, int n_in,
                              void* d_out, int out_size, void* d_ws, size_t ws_size,
                              hipStream_t stream) {
    const float* q = (const float*)d_in[0];
    const float* k = (const float*)d_in[1];
    const float* v = (const float*)d_in[2];
    const int* mask = (const int*)d_in[3];
    float* out = (float*)d_out;

    size_t elems = (size_t)Hh * Nn * Dd;
    size_t need = 2 * elems * sizeof(unsigned short);   // 32 MB (k16 + vt16)
    if (ws_size >= need) {
        unsigned short* k16 = (unsigned short*)d_ws;
        unsigned short* vt16 = k16 + elems;
        cvt_k<<<dim3((unsigned)(elems / 1024)), 256, 0, stream>>>(k, k16);
        cvt_vt<<<dim3(NB, Hh), 256, 0, stream>>>(v, vt16);
        attn32<<<dim3(Hh * NB / 2), 256, 0, stream>>>(k16, vt16, q, mask, out);
    } else {
        attn_main<<<dim3(Hh * NB), 256, 0, stream>>>(q, k, v, mask, out);
    }
}